// Round 9
// baseline (474.784 us; speedup 1.0000x reference)
//
#include <hip/hip_runtime.h>

// Problem constants (match reference file)
#define NN 100000
#define NE 1600000
#define NG 64

// dst-bucketing for the CSR build
#define BSHIFT 7
#define BUCKW (1 << BSHIFT)                 // 128 nodes per bucket
#define NBUCK ((NN + BUCKW - 1) >> BSHIFT)  // 782
#define BIN_CHUNK 8192

// ---------------- bucket histogram (LDS-aggregated, no per-node atomics) ----------------
__global__ __launch_bounds__(256) void bucket_hist_kernel(const int* __restrict__ dst,
                                                          int* __restrict__ bucket_cnt, int E) {
    __shared__ int h[NBUCK];
    for (int i = threadIdx.x; i < NBUCK; i += 256) h[i] = 0;
    __syncthreads();
    int stride = gridDim.x * 256;
    for (int e = blockIdx.x * 256 + threadIdx.x; e < E; e += stride)
        atomicAdd(&h[dst[e] >> BSHIFT], 1);
    __syncthreads();
    for (int i = threadIdx.x; i < NBUCK; i += 256)
        if (h[i]) atomicAdd(&bucket_cnt[i], h[i]);
}

// ---------------- bucket scan: single block (NBUCK <= 1024) ----------------
__global__ void bucket_scan_kernel(const int* __restrict__ bcnt, int* __restrict__ boff,
                                   int* __restrict__ bcur) {
    __shared__ int buf[2][1024];
    int t = threadIdx.x;
    int v = (t < NBUCK) ? bcnt[t] : 0;
    buf[0][t] = v;
    __syncthreads();
    int cur = 0;
    for (int off = 1; off < 1024; off <<= 1) {
        int x = buf[cur][t];
        if (t >= off) x += buf[cur][t - off];
        buf[cur ^ 1][t] = x;
        __syncthreads();
        cur ^= 1;
    }
    if (t < NBUCK) {
        int e = buf[cur][t] - v;
        boff[t] = e;
        bcur[t] = e;
    }
}

// ---------------- bin edges by dst-bucket (block-private sub-ranges) ----------------
__global__ __launch_bounds__(256) void bin_kernel(const int* __restrict__ src,
                                                  const int* __restrict__ dst,
                                                  int* __restrict__ bcur,
                                                  uint2* __restrict__ binned, int E) {
    __shared__ int h[NBUCK];
    __shared__ int cur[NBUCK];
    for (int i = threadIdx.x; i < NBUCK; i += 256) h[i] = 0;
    __syncthreads();
    int base = blockIdx.x * BIN_CHUNK;
    int end = base + BIN_CHUNK; if (end > E) end = E;
    for (int e = base + threadIdx.x; e < end; e += 256)
        atomicAdd(&h[dst[e] >> BSHIFT], 1);
    __syncthreads();
    for (int i = threadIdx.x; i < NBUCK; i += 256) {
        int c = h[i];
        cur[i] = c ? atomicAdd(&bcur[i], c) : 0;   // reserve contiguous sub-range
    }
    __syncthreads();
    for (int e = base + threadIdx.x; e < end; e += 256) {
        int s = src[e], d = dst[e];
        int pos = atomicAdd(&cur[d >> BSHIFT], 1);
        binned[pos] = make_uint2((unsigned)s, (unsigned)d);
    }
}

// ---------------- degree + dinv from binned edges (coalesced, LDS-only atomics) ----------
__global__ __launch_bounds__(256) void deg_dinv_kernel(const uint2* __restrict__ binned,
                                                       const int* __restrict__ bucket_off,
                                                       const int* __restrict__ bucket_cnt,
                                                       int* __restrict__ deg,
                                                       float* __restrict__ dinv, int n) {
    __shared__ int ldeg[BUCKW];
    int b = blockIdx.x;
    for (int i = threadIdx.x; i < BUCKW; i += 256) ldeg[i] = 0;
    __syncthreads();
    int start = bucket_off[b], cnt = bucket_cnt[b];
    for (int k = threadIdx.x; k < cnt; k += 256) {
        unsigned d = binned[start + k].y;
        atomicAdd(&ldeg[d & (BUCKW - 1)], 1);
    }
    __syncthreads();
    int v0 = b << BSHIFT;
    for (int i = threadIdx.x; i < BUCKW; i += 256) {
        int v = v0 + i;
        if (v < n) {
            int dg = ldeg[i];
            deg[v] = dg;
            dinv[v] = rsqrtf((float)dg + 1.0f);   // +1 = self loop
        }
    }
}

// ---------------- node scan (3 phases) ----------------
__global__ void scan1_kernel(const int* __restrict__ cntin, int* __restrict__ excl,
                             int* __restrict__ bsum, int n) {
    __shared__ int buf[2][1024];
    int t = threadIdx.x;
    int gid = blockIdx.x * 1024 + t;
    int v = (gid < n) ? cntin[gid] : 0;
    buf[0][t] = v;
    __syncthreads();
    int cur = 0;
    for (int off = 1; off < 1024; off <<= 1) {
        int x = buf[cur][t];
        if (t >= off) x += buf[cur][t - off];
        buf[cur ^ 1][t] = x;
        __syncthreads();
        cur ^= 1;
    }
    int incl = buf[cur][t];
    if (gid < n) excl[gid] = incl - v;          // within-block exclusive
    if (t == 1023) bsum[blockIdx.x] = incl;     // block total
}

__global__ void scan2_kernel(int* __restrict__ bsum, int nb) {   // one block of 128, nb<=128
    __shared__ int buf[2][128];
    int t = threadIdx.x;
    int v = (t < nb) ? bsum[t] : 0;
    buf[0][t] = v;
    __syncthreads();
    int cur = 0;
    for (int off = 1; off < 128; off <<= 1) {
        int x = buf[cur][t];
        if (t >= off) x += buf[cur][t - off];
        buf[cur ^ 1][t] = x;
        __syncthreads();
        cur ^= 1;
    }
    if (t < nb) bsum[t] = buf[cur][t] - v;      // exclusive block offsets
}

__global__ void scan3_kernel(int* __restrict__ excl, const int* __restrict__ bsum, int n) {
    int gid = blockIdx.x * blockDim.x + threadIdx.x;
    if (gid < n) excl[gid] += bsum[gid >> 10];
}

// ---------------- final CSR placement: one block per bucket, LDS cursors ----------------
__global__ __launch_bounds__(256) void build2_kernel(const uint2* __restrict__ binned,
                                                     const int* __restrict__ bucket_off,
                                                     const int* __restrict__ bucket_cnt,
                                                     const int* __restrict__ roff,
                                                     int* __restrict__ csr_src, int n) {
    __shared__ int lcur[BUCKW];
    int b = blockIdx.x;
    int v0 = b << BSHIFT;
    for (int i = threadIdx.x; i < BUCKW; i += 256) {
        int v = v0 + i;
        lcur[i] = (v < n) ? roff[v] : 0;
    }
    __syncthreads();
    int start = bucket_off[b], cnt = bucket_cnt[b];
    for (int k = threadIdx.x; k < cnt; k += 256) {
        uint2 e = binned[start + k];
        int pos = atomicAdd(&lcur[e.y & (BUCKW - 1)], 1);
        csr_src[pos] = (int)e.x;
    }
}

// ---------------- prescale layer-1 input: xs = dinv[v] * x[v] ----------------
__global__ void prescale_kernel(const float* __restrict__ x, const float* __restrict__ dinv,
                                float* __restrict__ xs, int n) {
    int i = blockIdx.x * blockDim.x + threadIdx.x;   // over n*2 float4s
    if (i >= n * 2) return;
    float dv = dinv[i >> 1];
    float4 v = ((const float4*)x)[i];
    ((float4*)xs)[i] = make_float4(v.x * dv, v.y * dv, v.z * dv, v.w * dv);
}

// ---------------- aggregation: out[v] = dinv[v] * (hs[v] + sum_in hs[src]) ----------------
template<int FIN>
__global__ void agg_kernel(const float* __restrict__ hs, const int* __restrict__ row_off,
                           const int* __restrict__ deg, const float* __restrict__ dinv,
                           const int* __restrict__ csr_src, float* __restrict__ out, int n) {
    constexpr int G = FIN / 4;
    int idx = blockIdx.x * blockDim.x + threadIdx.x;
    if (idx >= n * G) return;
    int v = idx / G;
    int c = idx % G;
    const float4* h4 = (const float4*)hs;
    float4 acc = h4[(size_t)v * G + c];               // self term (already scaled)
    int start = row_off[v], cnt = deg[v];
    const int* __restrict__ row = csr_src + start;
    int j = 0;
    for (; j + 4 <= cnt; j += 4) {
        int s0 = row[j], s1 = row[j + 1], s2 = row[j + 2], s3 = row[j + 3];
        float4 a0 = h4[(size_t)s0 * G + c];
        float4 a1 = h4[(size_t)s1 * G + c];
        float4 a2 = h4[(size_t)s2 * G + c];
        float4 a3 = h4[(size_t)s3 * G + c];
        float4 p0 = make_float4(a0.x + a1.x, a0.y + a1.y, a0.z + a1.z, a0.w + a1.w);
        float4 p1 = make_float4(a2.x + a3.x, a2.y + a3.y, a2.z + a3.z, a2.w + a3.w);
        acc.x += p0.x + p1.x; acc.y += p0.y + p1.y;
        acc.z += p0.z + p1.z; acc.w += p0.w + p1.w;
    }
    for (; j < cnt; ++j) {
        int s = row[j];
        float4 a = h4[(size_t)s * G + c];
        acc.x += a.x; acc.y += a.y; acc.z += a.z; acc.w += a.w;
    }
    float dv = dinv[v];
    ((float4*)out)[(size_t)v * G + c] =
        make_float4(acc.x * dv, acc.y * dv, acc.z * dv, acc.w * dv);
}

// ---------------- fused matmul + bias + prelu (+ optional dinv pre-scale of output) --------
template<int FIN, int FOUT, bool SCALE>
__global__ __launch_bounds__(256) void matmul_kernel(
    const float* __restrict__ tin, const float* __restrict__ W,
    const float* __restrict__ bias, const float* __restrict__ slope,
    const float* __restrict__ dinv, float* __restrict__ hout, int n) {
    constexpr int TPN = FOUT / 4;            // threads per node (4 outputs each)
    constexpr int NPB = (256 / TPN) * 4;     // nodes per block
    __shared__ float4 Wl[FIN * TPN];
    const float4* Wg = (const float4*)W;
    for (int i = threadIdx.x; i < FIN * TPN; i += 256) Wl[i] = Wg[i];
    __syncthreads();
    int t = threadIdx.x;
    int grp = t / TPN;
    int f4 = t % TPN;
    int v0 = blockIdx.x * NPB + grp * 4;
    float s = slope ? *slope : 1.0f;
    float4 bv = ((const float4*)bias)[f4];
    float4 acc[4];
#pragma unroll
    for (int nn = 0; nn < 4; ++nn) acc[nn] = bv;
    const float4* tin4 = (const float4*)tin;
#pragma unroll 2
    for (int i = 0; i < FIN; i += 4) {
        float4 r[4];
#pragma unroll
        for (int nn = 0; nn < 4; ++nn) {
            int v = v0 + nn;
            r[nn] = (v < n) ? tin4[(size_t)v * (FIN / 4) + (i >> 2)]
                            : make_float4(0.f, 0.f, 0.f, 0.f);
        }
#pragma unroll
        for (int k = 0; k < 4; ++k) {
            float4 wv = Wl[(i + k) * TPN + f4];
            float rk;
#pragma unroll
            for (int nn = 0; nn < 4; ++nn) {
                rk = (k == 0) ? r[nn].x : (k == 1) ? r[nn].y : (k == 2) ? r[nn].z : r[nn].w;
                acc[nn].x += wv.x * rk;
                acc[nn].y += wv.y * rk;
                acc[nn].z += wv.z * rk;
                acc[nn].w += wv.w * rk;
            }
        }
    }
#pragma unroll
    for (int nn = 0; nn < 4; ++nn) {
        int v = v0 + nn;
        if (v < n) {
            float m = SCALE ? dinv[v] : 1.0f;
            float4 o;
            o.x = (fmaxf(acc[nn].x, 0.f) + s * fminf(acc[nn].x, 0.f)) * m;
            o.y = (fmaxf(acc[nn].y, 0.f) + s * fminf(acc[nn].y, 0.f)) * m;
            o.z = (fmaxf(acc[nn].z, 0.f) + s * fminf(acc[nn].z, 0.f)) * m;
            o.w = (fmaxf(acc[nn].w, 0.f) + s * fminf(acc[nn].w, 0.f)) * m;
            ((float4*)hout)[(size_t)v * TPN + f4] = o;
        }
    }
}

// ---------------- fused layer-4 aggregation + pooling ----------------
// T[v] = dinv[v]*(hs[v] + sum_in hs[src]) never materialized; per-graph sums
// P[g] accumulate in registers (batch sorted), flushed on graph change.
// APCHUNK=64: 1563 blocks for occupancy; 16 row-streams x 16 float4-columns.
#define APCHUNK 64
__global__ __launch_bounds__(256) void agg_pool_kernel(
    const float* __restrict__ hs, const int* __restrict__ row_off,
    const int* __restrict__ deg, const float* __restrict__ dinv,
    const int* __restrict__ csr_src, const int* __restrict__ batch,
    float* __restrict__ sums, float* __restrict__ cnt, int n) {
    int tid = threadIdx.x;
    int c = tid & 15;        // float4 column (64 floats = 16 float4)
    int r = tid >> 4;        // row stream 0..15
    int start = blockIdx.x * APCHUNK;
    if (start >= n) return;
    int end = start + APCHUNK; if (end > n) end = n;
    const float4* h4 = (const float4*)hs;
    float4 pacc = make_float4(0.f, 0.f, 0.f, 0.f);
    float rc = 0.f;
    int curg = -1;
    for (int v = start + r; v < end; v += 16) {
        int g = batch[v];
        if (g != curg) {
            if (curg >= 0) {
                float* sp = &sums[curg * 64 + c * 4];
                atomicAdd(sp + 0, pacc.x); atomicAdd(sp + 1, pacc.y);
                atomicAdd(sp + 2, pacc.z); atomicAdd(sp + 3, pacc.w);
                if (c == 0) atomicAdd(&cnt[curg], rc);
                pacc = make_float4(0.f, 0.f, 0.f, 0.f); rc = 0.f;
            }
            curg = g;
        }
        // compute T[v] column c on the fly
        float4 acc = h4[(size_t)v * 16 + c];
        int s0 = row_off[v], dcnt = deg[v];
        const int* __restrict__ row = csr_src + s0;
        int j = 0;
        for (; j + 4 <= dcnt; j += 4) {
            int i0 = row[j], i1 = row[j + 1], i2 = row[j + 2], i3 = row[j + 3];
            float4 a0 = h4[(size_t)i0 * 16 + c];
            float4 a1 = h4[(size_t)i1 * 16 + c];
            float4 a2 = h4[(size_t)i2 * 16 + c];
            float4 a3 = h4[(size_t)i3 * 16 + c];
            acc.x += (a0.x + a1.x) + (a2.x + a3.x);
            acc.y += (a0.y + a1.y) + (a2.y + a3.y);
            acc.z += (a0.z + a1.z) + (a2.z + a3.z);
            acc.w += (a0.w + a1.w) + (a2.w + a3.w);
        }
        for (; j < dcnt; ++j) {
            int s = row[j];
            float4 a = h4[(size_t)s * 16 + c];
            acc.x += a.x; acc.y += a.y; acc.z += a.z; acc.w += a.w;
        }
        float dv = dinv[v];
        pacc.x += acc.x * dv; pacc.y += acc.y * dv;
        pacc.z += acc.z * dv; pacc.w += acc.w * dv;
        rc += 1.f;
    }
    if (curg >= 0) {
        float* sp = &sums[curg * 64 + c * 4];
        atomicAdd(sp + 0, pacc.x); atomicAdd(sp + 1, pacc.y);
        atomicAdd(sp + 2, pacc.z); atomicAdd(sp + 3, pacc.w);
        if (c == 0) atomicAdd(&cnt[curg], rc);
    }
}

// ---------------- head: out[g] = (P[g] @ (W4@Wlin)) / cnt[g] + (b4@Wlin + blin) ----------
__global__ __launch_bounds__(256) void head_kernel(
    const float* __restrict__ P, const float* __restrict__ cnt,
    const float* __restrict__ W4, const float* __restrict__ b4,
    const float* __restrict__ Wlin, const float* __restrict__ blin,
    float* __restrict__ out) {
    __shared__ float M[64 * 4];   // W4 @ Wlin
    __shared__ float bb[4];       // b4 @ Wlin + blin
    int t = threadIdx.x;          // 256 = 64 * 4
    {
        int k = t >> 2, cc = t & 3;
        float m = 0.f;
        for (int j = 0; j < 128; ++j) m += W4[k * 128 + j] * Wlin[j * 4 + cc];
        M[k * 4 + cc] = m;
    }
    if (t < 4) {
        float v = blin[t];
        for (int j = 0; j < 128; ++j) v += b4[j] * Wlin[j * 4 + t];
        bb[t] = v;
    }
    __syncthreads();
    int g = t >> 2, cc = t & 3;
    float a = 0.f;
    for (int k = 0; k < 64; ++k) a += P[g * 64 + k] * M[k * 4 + cc];
    out[g * 4 + cc] = a / fmaxf(cnt[g], 1.f) + bb[cc];
}

extern "C" void kernel_launch(void* const* d_in, const int* in_sizes, int n_in,
                              void* d_out, int out_size, void* d_ws, size_t ws_size,
                              hipStream_t stream) {
    const float* x    = (const float*)d_in[0];
    const int* esrc   = (const int*)d_in[1];
    const int* edst   = (const int*)d_in[2];
    const int* batch  = (const int*)d_in[3];
    const float* W1 = (const float*)d_in[4],  *b1 = (const float*)d_in[5];
    const float* W2 = (const float*)d_in[6],  *b2 = (const float*)d_in[7];
    const float* W3 = (const float*)d_in[8],  *b3 = (const float*)d_in[9];
    const float* W4 = (const float*)d_in[10], *b4 = (const float*)d_in[11];
    const float* a1 = (const float*)d_in[12];
    const float* a2 = (const float*)d_in[13];
    const float* a3 = (const float*)d_in[14];
    const float* Wlin = (const float*)d_in[15], *blin = (const float*)d_in[16];
    float* out = (float*)d_out;

    const int N = NN, E = NE;
    const int NB = (N + 1023) / 1024;           // node-scan blocks (98)
    const int NBIN = (E + BIN_CHUNK - 1) / BIN_CHUNK;   // 196

    // workspace carve-up
    char* w = (char*)d_ws;
    size_t off = 0;
    auto alloc = [&](size_t bytes) { size_t r = off; off += (bytes + 255) & ~(size_t)255; return r; };
    size_t o_bcnt = alloc((size_t)NBUCK * 4);      // needs zero
    size_t o_pool = alloc((size_t)NG * 64 * 4);    // needs zero (pooled T sums)
    size_t o_cnt  = alloc((size_t)NG * 4);         // needs zero
    size_t zero_bytes = off;
    size_t o_deg  = alloc((size_t)N * 4);
    size_t o_dinv = alloc((size_t)N * 4);
    size_t o_roff = alloc((size_t)N * 4);
    size_t o_boff = alloc((size_t)NBUCK * 4);
    size_t o_bcur = alloc((size_t)NBUCK * 4);
    size_t o_bsum = alloc((size_t)128 * 4);
    size_t o_csrc = alloc((size_t)E * 4);
    size_t o_bin  = alloc((size_t)E * 8);          // binned (src,dst) pairs
    size_t o_X    = alloc((size_t)N * 8 * 4);      // prescaled x
    size_t o_A    = alloc((size_t)N * 64 * 4);     // activations (max 64)
    size_t o_T    = alloc((size_t)N * 32 * 4);     // agg output (max 32)
    (void)ws_size;
    int*   bcnt   = (int*)(w + o_bcnt);
    float* pool   = (float*)(w + o_pool);
    float* cnt    = (float*)(w + o_cnt);
    int*   deg    = (int*)(w + o_deg);
    float* dinv   = (float*)(w + o_dinv);
    int*   roff   = (int*)(w + o_roff);
    int*   boff   = (int*)(w + o_boff);
    int*   bcur   = (int*)(w + o_bcur);
    int*   bsum   = (int*)(w + o_bsum);
    int*   csrc   = (int*)(w + o_csrc);
    uint2* binned = (uint2*)(w + o_bin);
    float* XS     = (float*)(w + o_X);
    float* A      = (float*)(w + o_A);
    float* T      = (float*)(w + o_T);

    hipMemsetAsync(w, 0, zero_bytes, stream);

    // ---- CSR build via dst-bucket binning (once, reused by all 4 layers) ----
    bucket_hist_kernel<<<256, 256, 0, stream>>>(edst, bcnt, E);
    bucket_scan_kernel<<<1, 1024, 0, stream>>>(bcnt, boff, bcur);
    bin_kernel<<<NBIN, 256, 0, stream>>>(esrc, edst, bcur, binned, E);
    deg_dinv_kernel<<<NBUCK, 256, 0, stream>>>(binned, boff, bcnt, deg, dinv, N);
    scan1_kernel<<<NB, 1024, 0, stream>>>(deg, roff, bsum, N);
    scan2_kernel<<<1, 128, 0, stream>>>(bsum, NB);
    scan3_kernel<<<(N + 255) / 256, 256, 0, stream>>>(roff, bsum, N);
    build2_kernel<<<NBUCK, 256, 0, stream>>>(binned, boff, bcnt, roff, csrc, N);

    // ---- layer 1: agg(dinv*x)[8] @ W1 -> 16, prelu a1, output pre-scaled ----
    prescale_kernel<<<(N * 2 + 255) / 256, 256, 0, stream>>>(x, dinv, XS, N);
    agg_kernel<8><<<(N * 2 + 255) / 256, 256, 0, stream>>>(XS, roff, deg, dinv, csrc, T, N);
    {   constexpr int npb = (256 / (16 / 4)) * 4;   // 256
        matmul_kernel<8, 16, true><<<(N + npb - 1) / npb, 256, 0, stream>>>(T, W1, b1, a1, dinv, A, N); }

    // ---- layer 2 ----
    agg_kernel<16><<<(N * 4 + 255) / 256, 256, 0, stream>>>(A, roff, deg, dinv, csrc, T, N);
    {   constexpr int npb = (256 / (32 / 4)) * 4;   // 128
        matmul_kernel<16, 32, true><<<(N + npb - 1) / npb, 256, 0, stream>>>(T, W2, b2, a2, dinv, A, N); }

    // ---- layer 3 ----
    agg_kernel<32><<<(N * 8 + 255) / 256, 256, 0, stream>>>(A, roff, deg, dinv, csrc, T, N);
    {   constexpr int npb = (256 / (64 / 4)) * 4;   // 64
        matmul_kernel<32, 64, true><<<(N + npb - 1) / npb, 256, 0, stream>>>(T, W3, b3, a3, dinv, A, N); }

    // ---- layer 4: fused agg + pool (T never materialized; matmul folded into head) ----
    agg_pool_kernel<<<(N + APCHUNK - 1) / APCHUNK, 256, 0, stream>>>(
        A, roff, deg, dinv, csrc, batch, pool, cnt, N);
    head_kernel<<<1, 256, 0, stream>>>(pool, cnt, W4, b4, Wlin, blin, out);
}

// Round 10
// 338.557 us; speedup vs baseline: 1.4024x; 1.4024x over previous
//
#include <hip/hip_runtime.h>

// Problem constants (match reference file)
#define NN 100000
#define NE 1600000
#define NG 64

// dst-bucketing for the CSR build
#define BSHIFT 7
#define BUCKW (1 << BSHIFT)                 // 128 nodes per bucket
#define NBUCK ((NN + BUCKW - 1) >> BSHIFT)  // 782
#define BIN_CHUNK 8192

// ---------------- bucket histogram (LDS-aggregated, no per-node atomics) ----------------
__global__ __launch_bounds__(256) void bucket_hist_kernel(const int* __restrict__ dst,
                                                          int* __restrict__ bucket_cnt, int E) {
    __shared__ int h[NBUCK];
    for (int i = threadIdx.x; i < NBUCK; i += 256) h[i] = 0;
    __syncthreads();
    int stride = gridDim.x * 256;
    for (int e = blockIdx.x * 256 + threadIdx.x; e < E; e += stride)
        atomicAdd(&h[dst[e] >> BSHIFT], 1);
    __syncthreads();
    for (int i = threadIdx.x; i < NBUCK; i += 256)
        if (h[i]) atomicAdd(&bucket_cnt[i], h[i]);
}

// ---------------- bucket scan: single block (NBUCK <= 1024) ----------------
__global__ void bucket_scan_kernel(const int* __restrict__ bcnt, int* __restrict__ boff,
                                   int* __restrict__ bcur) {
    __shared__ int buf[2][1024];
    int t = threadIdx.x;
    int v = (t < NBUCK) ? bcnt[t] : 0;
    buf[0][t] = v;
    __syncthreads();
    int cur = 0;
    for (int off = 1; off < 1024; off <<= 1) {
        int x = buf[cur][t];
        if (t >= off) x += buf[cur][t - off];
        buf[cur ^ 1][t] = x;
        __syncthreads();
        cur ^= 1;
    }
    if (t < NBUCK) {
        int e = buf[cur][t] - v;
        boff[t] = e;
        bcur[t] = e;
    }
}

// ---------------- bin edges by dst-bucket (block-private sub-ranges) ----------------
__global__ __launch_bounds__(256) void bin_kernel(const int* __restrict__ src,
                                                  const int* __restrict__ dst,
                                                  int* __restrict__ bcur,
                                                  uint2* __restrict__ binned, int E) {
    __shared__ int h[NBUCK];
    __shared__ int cur[NBUCK];
    for (int i = threadIdx.x; i < NBUCK; i += 256) h[i] = 0;
    __syncthreads();
    int base = blockIdx.x * BIN_CHUNK;
    int end = base + BIN_CHUNK; if (end > E) end = E;
    for (int e = base + threadIdx.x; e < end; e += 256)
        atomicAdd(&h[dst[e] >> BSHIFT], 1);
    __syncthreads();
    for (int i = threadIdx.x; i < NBUCK; i += 256) {
        int c = h[i];
        cur[i] = c ? atomicAdd(&bcur[i], c) : 0;   // reserve contiguous sub-range
    }
    __syncthreads();
    for (int e = base + threadIdx.x; e < end; e += 256) {
        int s = src[e], d = dst[e];
        int pos = atomicAdd(&cur[d >> BSHIFT], 1);
        binned[pos] = make_uint2((unsigned)s, (unsigned)d);
    }
}

// ---------------- degree + dinv from binned edges (coalesced, LDS-only atomics) ----------
__global__ __launch_bounds__(256) void deg_dinv_kernel(const uint2* __restrict__ binned,
                                                       const int* __restrict__ bucket_off,
                                                       const int* __restrict__ bucket_cnt,
                                                       int* __restrict__ deg,
                                                       float* __restrict__ dinv, int n) {
    __shared__ int ldeg[BUCKW];
    int b = blockIdx.x;
    for (int i = threadIdx.x; i < BUCKW; i += 256) ldeg[i] = 0;
    __syncthreads();
    int start = bucket_off[b], cnt = bucket_cnt[b];
    for (int k = threadIdx.x; k < cnt; k += 256) {
        unsigned d = binned[start + k].y;
        atomicAdd(&ldeg[d & (BUCKW - 1)], 1);
    }
    __syncthreads();
    int v0 = b << BSHIFT;
    for (int i = threadIdx.x; i < BUCKW; i += 256) {
        int v = v0 + i;
        if (v < n) {
            int dg = ldeg[i];
            deg[v] = dg;
            dinv[v] = rsqrtf((float)dg + 1.0f);   // +1 = self loop
        }
    }
}

// ---------------- node scan (3 phases) ----------------
__global__ void scan1_kernel(const int* __restrict__ cntin, int* __restrict__ excl,
                             int* __restrict__ bsum, int n) {
    __shared__ int buf[2][1024];
    int t = threadIdx.x;
    int gid = blockIdx.x * 1024 + t;
    int v = (gid < n) ? cntin[gid] : 0;
    buf[0][t] = v;
    __syncthreads();
    int cur = 0;
    for (int off = 1; off < 1024; off <<= 1) {
        int x = buf[cur][t];
        if (t >= off) x += buf[cur][t - off];
        buf[cur ^ 1][t] = x;
        __syncthreads();
        cur ^= 1;
    }
    int incl = buf[cur][t];
    if (gid < n) excl[gid] = incl - v;          // within-block exclusive
    if (t == 1023) bsum[blockIdx.x] = incl;     // block total
}

__global__ void scan2_kernel(int* __restrict__ bsum, int nb) {   // one block of 128, nb<=128
    __shared__ int buf[2][128];
    int t = threadIdx.x;
    int v = (t < nb) ? bsum[t] : 0;
    buf[0][t] = v;
    __syncthreads();
    int cur = 0;
    for (int off = 1; off < 128; off <<= 1) {
        int x = buf[cur][t];
        if (t >= off) x += buf[cur][t - off];
        buf[cur ^ 1][t] = x;
        __syncthreads();
        cur ^= 1;
    }
    if (t < nb) bsum[t] = buf[cur][t] - v;      // exclusive block offsets
}

__global__ void scan3_kernel(int* __restrict__ excl, const int* __restrict__ bsum, int n) {
    int gid = blockIdx.x * blockDim.x + threadIdx.x;
    if (gid < n) excl[gid] += bsum[gid >> 10];
}

// ---------------- final CSR placement: one block per bucket, LDS cursors ----------------
__global__ __launch_bounds__(256) void build2_kernel(const uint2* __restrict__ binned,
                                                     const int* __restrict__ bucket_off,
                                                     const int* __restrict__ bucket_cnt,
                                                     const int* __restrict__ roff,
                                                     int* __restrict__ csr_src, int n) {
    __shared__ int lcur[BUCKW];
    int b = blockIdx.x;
    int v0 = b << BSHIFT;
    for (int i = threadIdx.x; i < BUCKW; i += 256) {
        int v = v0 + i;
        lcur[i] = (v < n) ? roff[v] : 0;
    }
    __syncthreads();
    int start = bucket_off[b], cnt = bucket_cnt[b];
    for (int k = threadIdx.x; k < cnt; k += 256) {
        uint2 e = binned[start + k];
        int pos = atomicAdd(&lcur[e.y & (BUCKW - 1)], 1);
        csr_src[pos] = (int)e.x;
    }
}

// ---------------- prescale layer-1 input: xs = dinv[v] * x[v] ----------------
__global__ void prescale_kernel(const float* __restrict__ x, const float* __restrict__ dinv,
                                float* __restrict__ xs, int n) {
    int i = blockIdx.x * blockDim.x + threadIdx.x;   // over n*2 float4s
    if (i >= n * 2) return;
    float dv = dinv[i >> 1];
    float4 v = ((const float4*)x)[i];
    ((float4*)xs)[i] = make_float4(v.x * dv, v.y * dv, v.z * dv, v.w * dv);
}

// ---------------- aggregation: out[v] = dinv[v] * (hs[v] + sum_in hs[src]) ----------------
template<int FIN>
__global__ void agg_kernel(const float* __restrict__ hs, const int* __restrict__ row_off,
                           const int* __restrict__ deg, const float* __restrict__ dinv,
                           const int* __restrict__ csr_src, float* __restrict__ out, int n) {
    constexpr int G = FIN / 4;
    int idx = blockIdx.x * blockDim.x + threadIdx.x;
    if (idx >= n * G) return;
    int v = idx / G;
    int c = idx % G;
    const float4* h4 = (const float4*)hs;
    float4 acc = h4[(size_t)v * G + c];               // self term (already scaled)
    int start = row_off[v], cnt = deg[v];
    const int* __restrict__ row = csr_src + start;
    int j = 0;
    for (; j + 4 <= cnt; j += 4) {
        int s0 = row[j], s1 = row[j + 1], s2 = row[j + 2], s3 = row[j + 3];
        float4 a0 = h4[(size_t)s0 * G + c];
        float4 a1 = h4[(size_t)s1 * G + c];
        float4 a2 = h4[(size_t)s2 * G + c];
        float4 a3 = h4[(size_t)s3 * G + c];
        float4 p0 = make_float4(a0.x + a1.x, a0.y + a1.y, a0.z + a1.z, a0.w + a1.w);
        float4 p1 = make_float4(a2.x + a3.x, a2.y + a3.y, a2.z + a3.z, a2.w + a3.w);
        acc.x += p0.x + p1.x; acc.y += p0.y + p1.y;
        acc.z += p0.z + p1.z; acc.w += p0.w + p1.w;
    }
    for (; j < cnt; ++j) {
        int s = row[j];
        float4 a = h4[(size_t)s * G + c];
        acc.x += a.x; acc.y += a.y; acc.z += a.z; acc.w += a.w;
    }
    float dv = dinv[v];
    ((float4*)out)[(size_t)v * G + c] =
        make_float4(acc.x * dv, acc.y * dv, acc.z * dv, acc.w * dv);
}

// ---------------- fused matmul + bias + prelu (+ optional dinv pre-scale of output) --------
template<int FIN, int FOUT, bool SCALE>
__global__ __launch_bounds__(256) void matmul_kernel(
    const float* __restrict__ tin, const float* __restrict__ W,
    const float* __restrict__ bias, const float* __restrict__ slope,
    const float* __restrict__ dinv, float* __restrict__ hout, int n) {
    constexpr int TPN = FOUT / 4;            // threads per node (4 outputs each)
    constexpr int NPB = (256 / TPN) * 4;     // nodes per block
    __shared__ float4 Wl[FIN * TPN];
    const float4* Wg = (const float4*)W;
    for (int i = threadIdx.x; i < FIN * TPN; i += 256) Wl[i] = Wg[i];
    __syncthreads();
    int t = threadIdx.x;
    int grp = t / TPN;
    int f4 = t % TPN;
    int v0 = blockIdx.x * NPB + grp * 4;
    float s = slope ? *slope : 1.0f;
    float4 bv = ((const float4*)bias)[f4];
    float4 acc[4];
#pragma unroll
    for (int nn = 0; nn < 4; ++nn) acc[nn] = bv;
    const float4* tin4 = (const float4*)tin;
#pragma unroll 2
    for (int i = 0; i < FIN; i += 4) {
        float4 r[4];
#pragma unroll
        for (int nn = 0; nn < 4; ++nn) {
            int v = v0 + nn;
            r[nn] = (v < n) ? tin4[(size_t)v * (FIN / 4) + (i >> 2)]
                            : make_float4(0.f, 0.f, 0.f, 0.f);
        }
#pragma unroll
        for (int k = 0; k < 4; ++k) {
            float4 wv = Wl[(i + k) * TPN + f4];
            float rk;
#pragma unroll
            for (int nn = 0; nn < 4; ++nn) {
                rk = (k == 0) ? r[nn].x : (k == 1) ? r[nn].y : (k == 2) ? r[nn].z : r[nn].w;
                acc[nn].x += wv.x * rk;
                acc[nn].y += wv.y * rk;
                acc[nn].z += wv.z * rk;
                acc[nn].w += wv.w * rk;
            }
        }
    }
#pragma unroll
    for (int nn = 0; nn < 4; ++nn) {
        int v = v0 + nn;
        if (v < n) {
            float m = SCALE ? dinv[v] : 1.0f;
            float4 o;
            o.x = (fmaxf(acc[nn].x, 0.f) + s * fminf(acc[nn].x, 0.f)) * m;
            o.y = (fmaxf(acc[nn].y, 0.f) + s * fminf(acc[nn].y, 0.f)) * m;
            o.z = (fmaxf(acc[nn].z, 0.f) + s * fminf(acc[nn].z, 0.f)) * m;
            o.w = (fmaxf(acc[nn].w, 0.f) + s * fminf(acc[nn].w, 0.f)) * m;
            ((float4*)hout)[(size_t)v * TPN + f4] = o;
        }
    }
}

// ---------------- fused layer-4 aggregation + pooling (LDS-reduced flush) ----------------
// T[v] = dinv[v]*(hs[v] + sum_in hs[src]) never materialized. Per-thread register
// partials dump into LDS lacc[64 graphs][16 float4 cols] on graph change (LDS atomics);
// block flushes ONLY graphs in [batch[start], batch[end-1]] -> ~2*64 global atomics/block.
#define APCHUNK 64
__global__ __launch_bounds__(256) void agg_pool_kernel(
    const float* __restrict__ hs, const int* __restrict__ row_off,
    const int* __restrict__ deg, const float* __restrict__ dinv,
    const int* __restrict__ csr_src, const int* __restrict__ batch,
    float* __restrict__ sums, float* __restrict__ cnt, int n) {
    __shared__ float lacc[NG * 64];   // [graph][feature] 16 KB
    __shared__ float lcnt[NG];
    int tid = threadIdx.x;
    int c = tid & 15;        // float4 column (64 floats = 16 float4)
    int r = tid >> 4;        // row stream 0..15
    int start = blockIdx.x * APCHUNK;
    if (start >= n) return;
    int end = start + APCHUNK; if (end > n) end = n;
    for (int i = tid; i < NG * 64; i += 256) lacc[i] = 0.f;
    if (tid < NG) lcnt[tid] = 0.f;
    __syncthreads();
    const float4* h4 = (const float4*)hs;
    float4 pacc = make_float4(0.f, 0.f, 0.f, 0.f);
    float rc = 0.f;
    int curg = -1;
    for (int v = start + r; v < end; v += 16) {
        int g = batch[v];
        if (g != curg) {
            if (curg >= 0) {
                float* lp = &lacc[curg * 64 + c * 4];
                atomicAdd(lp + 0, pacc.x); atomicAdd(lp + 1, pacc.y);
                atomicAdd(lp + 2, pacc.z); atomicAdd(lp + 3, pacc.w);
                if (c == 0) atomicAdd(&lcnt[curg], rc);
                pacc = make_float4(0.f, 0.f, 0.f, 0.f); rc = 0.f;
            }
            curg = g;
        }
        // compute T[v] column c on the fly
        float4 acc = h4[(size_t)v * 16 + c];
        int s0 = row_off[v], dcnt = deg[v];
        const int* __restrict__ row = csr_src + s0;
        int j = 0;
        for (; j + 4 <= dcnt; j += 4) {
            int i0 = row[j], i1 = row[j + 1], i2 = row[j + 2], i3 = row[j + 3];
            float4 a0 = h4[(size_t)i0 * 16 + c];
            float4 a1 = h4[(size_t)i1 * 16 + c];
            float4 a2 = h4[(size_t)i2 * 16 + c];
            float4 a3 = h4[(size_t)i3 * 16 + c];
            acc.x += (a0.x + a1.x) + (a2.x + a3.x);
            acc.y += (a0.y + a1.y) + (a2.y + a3.y);
            acc.z += (a0.z + a1.z) + (a2.z + a3.z);
            acc.w += (a0.w + a1.w) + (a2.w + a3.w);
        }
        for (; j < dcnt; ++j) {
            int s = row[j];
            float4 a = h4[(size_t)s * 16 + c];
            acc.x += a.x; acc.y += a.y; acc.z += a.z; acc.w += a.w;
        }
        float dv = dinv[v];
        pacc.x += acc.x * dv; pacc.y += acc.y * dv;
        pacc.z += acc.z * dv; pacc.w += acc.w * dv;
        rc += 1.f;
    }
    if (curg >= 0) {
        float* lp = &lacc[curg * 64 + c * 4];
        atomicAdd(lp + 0, pacc.x); atomicAdd(lp + 1, pacc.y);
        atomicAdd(lp + 2, pacc.z); atomicAdd(lp + 3, pacc.w);
        if (c == 0) atomicAdd(&lcnt[curg], rc);
    }
    __syncthreads();
    // flush only graphs present in this block's node range (batch sorted)
    int gmin = batch[start];
    int gmax = batch[end - 1];
    int span = gmax - gmin + 1;
    for (int idx = tid; idx < span * 64; idx += 256) {
        int g = gmin + idx / 64;
        int f = idx % 64;
        float val = lacc[g * 64 + f];
        if (val != 0.f) atomicAdd(&sums[g * 64 + f], val);
    }
    for (int g = gmin + tid; g <= gmax; g += 256) {
        float v = lcnt[g];
        if (v != 0.f) atomicAdd(&cnt[g], v);
    }
}

// ---------------- head: out[g] = (P[g] @ (W4@Wlin)) / cnt[g] + (b4@Wlin + blin) ----------
__global__ __launch_bounds__(256) void head_kernel(
    const float* __restrict__ P, const float* __restrict__ cnt,
    const float* __restrict__ W4, const float* __restrict__ b4,
    const float* __restrict__ Wlin, const float* __restrict__ blin,
    float* __restrict__ out) {
    __shared__ float M[64 * 4];   // W4 @ Wlin
    __shared__ float bb[4];       // b4 @ Wlin + blin
    int t = threadIdx.x;          // 256 = 64 * 4
    {
        int k = t >> 2, cc = t & 3;
        float m = 0.f;
        for (int j = 0; j < 128; ++j) m += W4[k * 128 + j] * Wlin[j * 4 + cc];
        M[k * 4 + cc] = m;
    }
    if (t < 4) {
        float v = blin[t];
        for (int j = 0; j < 128; ++j) v += b4[j] * Wlin[j * 4 + t];
        bb[t] = v;
    }
    __syncthreads();
    int g = t >> 2, cc = t & 3;
    float a = 0.f;
    for (int k = 0; k < 64; ++k) a += P[g * 64 + k] * M[k * 4 + cc];
    out[g * 4 + cc] = a / fmaxf(cnt[g], 1.f) + bb[cc];
}

extern "C" void kernel_launch(void* const* d_in, const int* in_sizes, int n_in,
                              void* d_out, int out_size, void* d_ws, size_t ws_size,
                              hipStream_t stream) {
    const float* x    = (const float*)d_in[0];
    const int* esrc   = (const int*)d_in[1];
    const int* edst   = (const int*)d_in[2];
    const int* batch  = (const int*)d_in[3];
    const float* W1 = (const float*)d_in[4],  *b1 = (const float*)d_in[5];
    const float* W2 = (const float*)d_in[6],  *b2 = (const float*)d_in[7];
    const float* W3 = (const float*)d_in[8],  *b3 = (const float*)d_in[9];
    const float* W4 = (const float*)d_in[10], *b4 = (const float*)d_in[11];
    const float* a1 = (const float*)d_in[12];
    const float* a2 = (const float*)d_in[13];
    const float* a3 = (const float*)d_in[14];
    const float* Wlin = (const float*)d_in[15], *blin = (const float*)d_in[16];
    float* out = (float*)d_out;

    const int N = NN, E = NE;
    const int NB = (N + 1023) / 1024;           // node-scan blocks (98)
    const int NBIN = (E + BIN_CHUNK - 1) / BIN_CHUNK;   // 196

    // workspace carve-up
    char* w = (char*)d_ws;
    size_t off = 0;
    auto alloc = [&](size_t bytes) { size_t r = off; off += (bytes + 255) & ~(size_t)255; return r; };
    size_t o_bcnt = alloc((size_t)NBUCK * 4);      // needs zero
    size_t o_pool = alloc((size_t)NG * 64 * 4);    // needs zero (pooled T sums)
    size_t o_cnt  = alloc((size_t)NG * 4);         // needs zero
    size_t zero_bytes = off;
    size_t o_deg  = alloc((size_t)N * 4);
    size_t o_dinv = alloc((size_t)N * 4);
    size_t o_roff = alloc((size_t)N * 4);
    size_t o_boff = alloc((size_t)NBUCK * 4);
    size_t o_bcur = alloc((size_t)NBUCK * 4);
    size_t o_bsum = alloc((size_t)128 * 4);
    size_t o_csrc = alloc((size_t)E * 4);
    size_t o_bin  = alloc((size_t)E * 8);          // binned (src,dst) pairs
    size_t o_X    = alloc((size_t)N * 8 * 4);      // prescaled x
    size_t o_A    = alloc((size_t)N * 64 * 4);     // activations (max 64)
    size_t o_T    = alloc((size_t)N * 32 * 4);     // agg output (max 32)
    (void)ws_size;
    int*   bcnt   = (int*)(w + o_bcnt);
    float* pool   = (float*)(w + o_pool);
    float* cnt    = (float*)(w + o_cnt);
    int*   deg    = (int*)(w + o_deg);
    float* dinv   = (float*)(w + o_dinv);
    int*   roff   = (int*)(w + o_roff);
    int*   boff   = (int*)(w + o_boff);
    int*   bcur   = (int*)(w + o_bcur);
    int*   bsum   = (int*)(w + o_bsum);
    int*   csrc   = (int*)(w + o_csrc);
    uint2* binned = (uint2*)(w + o_bin);
    float* XS     = (float*)(w + o_X);
    float* A      = (float*)(w + o_A);
    float* T      = (float*)(w + o_T);

    hipMemsetAsync(w, 0, zero_bytes, stream);

    // ---- CSR build via dst-bucket binning (once, reused by all 4 layers) ----
    bucket_hist_kernel<<<256, 256, 0, stream>>>(edst, bcnt, E);
    bucket_scan_kernel<<<1, 1024, 0, stream>>>(bcnt, boff, bcur);
    bin_kernel<<<NBIN, 256, 0, stream>>>(esrc, edst, bcur, binned, E);
    deg_dinv_kernel<<<NBUCK, 256, 0, stream>>>(binned, boff, bcnt, deg, dinv, N);
    scan1_kernel<<<NB, 1024, 0, stream>>>(deg, roff, bsum, N);
    scan2_kernel<<<1, 128, 0, stream>>>(bsum, NB);
    scan3_kernel<<<(N + 255) / 256, 256, 0, stream>>>(roff, bsum, N);
    build2_kernel<<<NBUCK, 256, 0, stream>>>(binned, boff, bcnt, roff, csrc, N);

    // ---- layer 1: agg(dinv*x)[8] @ W1 -> 16, prelu a1, output pre-scaled ----
    prescale_kernel<<<(N * 2 + 255) / 256, 256, 0, stream>>>(x, dinv, XS, N);
    agg_kernel<8><<<(N * 2 + 255) / 256, 256, 0, stream>>>(XS, roff, deg, dinv, csrc, T, N);
    {   constexpr int npb = (256 / (16 / 4)) * 4;   // 256
        matmul_kernel<8, 16, true><<<(N + npb - 1) / npb, 256, 0, stream>>>(T, W1, b1, a1, dinv, A, N); }

    // ---- layer 2 ----
    agg_kernel<16><<<(N * 4 + 255) / 256, 256, 0, stream>>>(A, roff, deg, dinv, csrc, T, N);
    {   constexpr int npb = (256 / (32 / 4)) * 4;   // 128
        matmul_kernel<16, 32, true><<<(N + npb - 1) / npb, 256, 0, stream>>>(T, W2, b2, a2, dinv, A, N); }

    // ---- layer 3 ----
    agg_kernel<32><<<(N * 8 + 255) / 256, 256, 0, stream>>>(A, roff, deg, dinv, csrc, T, N);
    {   constexpr int npb = (256 / (64 / 4)) * 4;   // 64
        matmul_kernel<32, 64, true><<<(N + npb - 1) / npb, 256, 0, stream>>>(T, W3, b3, a3, dinv, A, N); }

    // ---- layer 4: fused agg + pool (T never materialized; matmul folded into head) ----
    agg_pool_kernel<<<(N + APCHUNK - 1) / APCHUNK, 256, 0, stream>>>(
        A, roff, deg, dinv, csrc, batch, pool, cnt, N);
    head_kernel<<<1, 256, 0, stream>>>(pool, cnt, W4, b4, Wlin, blin, out);
}

// Round 11
// 296.418 us; speedup vs baseline: 1.6017x; 1.1422x over previous
//
#include <hip/hip_runtime.h>
#include <hip/hip_fp16.h>

// Problem constants (match reference file)
#define NN 100000
#define NE 1600000
#define NG 64

// dst-bucketing for the CSR build
#define BSHIFT 7
#define BUCKW (1 << BSHIFT)                 // 128 nodes per bucket
#define NBUCK ((NN + BUCKW - 1) >> BSHIFT)  // 782
#define BIN_CHUNK 8192

// ---- fp16 8-wide helpers (activations stored fp16, math in fp32) ----
union H8 { float4 f4; __half2 h2[4]; };
__device__ __forceinline__ void h8_to_f(const H8& h, float* f) {
    float2 a = __half22float2(h.h2[0]);
    float2 b = __half22float2(h.h2[1]);
    float2 c = __half22float2(h.h2[2]);
    float2 d = __half22float2(h.h2[3]);
    f[0]=a.x; f[1]=a.y; f[2]=b.x; f[3]=b.y; f[4]=c.x; f[5]=c.y; f[6]=d.x; f[7]=d.y;
}
__device__ __forceinline__ H8 f_to_h8(const float* f) {
    H8 h;
    h.h2[0] = __floats2half2_rn(f[0], f[1]);
    h.h2[1] = __floats2half2_rn(f[2], f[3]);
    h.h2[2] = __floats2half2_rn(f[4], f[5]);
    h.h2[3] = __floats2half2_rn(f[6], f[7]);
    return h;
}

// ---------------- bucket histogram (LDS-aggregated) ----------------
__global__ __launch_bounds__(256) void bucket_hist_kernel(const int* __restrict__ dst,
                                                          int* __restrict__ bucket_cnt, int E) {
    __shared__ int h[NBUCK];
    for (int i = threadIdx.x; i < NBUCK; i += 256) h[i] = 0;
    __syncthreads();
    int stride = gridDim.x * 256;
    for (int e = blockIdx.x * 256 + threadIdx.x; e < E; e += stride)
        atomicAdd(&h[dst[e] >> BSHIFT], 1);
    __syncthreads();
    for (int i = threadIdx.x; i < NBUCK; i += 256)
        if (h[i]) atomicAdd(&bucket_cnt[i], h[i]);
}

// ---------------- bucket scan: single block ----------------
__global__ void bucket_scan_kernel(const int* __restrict__ bcnt, int* __restrict__ boff,
                                   int* __restrict__ bcur) {
    __shared__ int buf[2][1024];
    int t = threadIdx.x;
    int v = (t < NBUCK) ? bcnt[t] : 0;
    buf[0][t] = v;
    __syncthreads();
    int cur = 0;
    for (int off = 1; off < 1024; off <<= 1) {
        int x = buf[cur][t];
        if (t >= off) x += buf[cur][t - off];
        buf[cur ^ 1][t] = x;
        __syncthreads();
        cur ^= 1;
    }
    if (t < NBUCK) {
        int e = buf[cur][t] - v;
        boff[t] = e;
        bcur[t] = e;
    }
}

// ---------------- bin edges by dst-bucket; packed (src<<7)|dst_low ----------------
__global__ __launch_bounds__(256) void bin_kernel(const int* __restrict__ src,
                                                  const int* __restrict__ dst,
                                                  int* __restrict__ bcur,
                                                  unsigned* __restrict__ binned, int E) {
    __shared__ int h[NBUCK];
    __shared__ int cur[NBUCK];
    for (int i = threadIdx.x; i < NBUCK; i += 256) h[i] = 0;
    __syncthreads();
    int base = blockIdx.x * BIN_CHUNK;
    int end = base + BIN_CHUNK; if (end > E) end = E;
    for (int e = base + threadIdx.x; e < end; e += 256)
        atomicAdd(&h[dst[e] >> BSHIFT], 1);
    __syncthreads();
    for (int i = threadIdx.x; i < NBUCK; i += 256) {
        int c = h[i];
        cur[i] = c ? atomicAdd(&bcur[i], c) : 0;   // reserve contiguous sub-range
    }
    __syncthreads();
    for (int e = base + threadIdx.x; e < end; e += 256) {
        unsigned s = (unsigned)src[e], d = (unsigned)dst[e];
        int pos = atomicAdd(&cur[d >> BSHIFT], 1);
        binned[pos] = (s << BSHIFT) | (d & (BUCKW - 1));
    }
}

// ---------------- degree + dinv from binned edges ----------------
__global__ __launch_bounds__(256) void deg_dinv_kernel(const unsigned* __restrict__ binned,
                                                       const int* __restrict__ bucket_off,
                                                       const int* __restrict__ bucket_cnt,
                                                       int* __restrict__ deg,
                                                       float* __restrict__ dinv, int n) {
    __shared__ int ldeg[BUCKW];
    int b = blockIdx.x;
    for (int i = threadIdx.x; i < BUCKW; i += 256) ldeg[i] = 0;
    __syncthreads();
    int start = bucket_off[b], cnt = bucket_cnt[b];
    for (int k = threadIdx.x; k < cnt; k += 256)
        atomicAdd(&ldeg[binned[start + k] & (BUCKW - 1)], 1);
    __syncthreads();
    int v0 = b << BSHIFT;
    for (int i = threadIdx.x; i < BUCKW; i += 256) {
        int v = v0 + i;
        if (v < n) {
            int dg = ldeg[i];
            deg[v] = dg;
            dinv[v] = rsqrtf((float)dg + 1.0f);   // +1 = self loop
        }
    }
}

// ---------------- node scan (3 phases) ----------------
__global__ void scan1_kernel(const int* __restrict__ cntin, int* __restrict__ excl,
                             int* __restrict__ bsum, int n) {
    __shared__ int buf[2][1024];
    int t = threadIdx.x;
    int gid = blockIdx.x * 1024 + t;
    int v = (gid < n) ? cntin[gid] : 0;
    buf[0][t] = v;
    __syncthreads();
    int cur = 0;
    for (int off = 1; off < 1024; off <<= 1) {
        int x = buf[cur][t];
        if (t >= off) x += buf[cur][t - off];
        buf[cur ^ 1][t] = x;
        __syncthreads();
        cur ^= 1;
    }
    int incl = buf[cur][t];
    if (gid < n) excl[gid] = incl - v;
    if (t == 1023) bsum[blockIdx.x] = incl;
}

__global__ void scan2_kernel(int* __restrict__ bsum, int nb) {
    __shared__ int buf[2][128];
    int t = threadIdx.x;
    int v = (t < nb) ? bsum[t] : 0;
    buf[0][t] = v;
    __syncthreads();
    int cur = 0;
    for (int off = 1; off < 128; off <<= 1) {
        int x = buf[cur][t];
        if (t >= off) x += buf[cur][t - off];
        buf[cur ^ 1][t] = x;
        __syncthreads();
        cur ^= 1;
    }
    if (t < nb) bsum[t] = buf[cur][t] - v;
}

__global__ void scan3_kernel(int* __restrict__ excl, const int* __restrict__ bsum, int n) {
    int gid = blockIdx.x * blockDim.x + threadIdx.x;
    if (gid < n) excl[gid] += bsum[gid >> 10];
}

// ---------------- final CSR placement ----------------
__global__ __launch_bounds__(256) void build2_kernel(const unsigned* __restrict__ binned,
                                                     const int* __restrict__ bucket_off,
                                                     const int* __restrict__ bucket_cnt,
                                                     const int* __restrict__ roff,
                                                     int* __restrict__ csr_src, int n) {
    __shared__ int lcur[BUCKW];
    int b = blockIdx.x;
    int v0 = b << BSHIFT;
    for (int i = threadIdx.x; i < BUCKW; i += 256) {
        int v = v0 + i;
        lcur[i] = (v < n) ? roff[v] : 0;
    }
    __syncthreads();
    int start = bucket_off[b], cnt = bucket_cnt[b];
    for (int k = threadIdx.x; k < cnt; k += 256) {
        unsigned e = binned[start + k];
        int pos = atomicAdd(&lcur[e & (BUCKW - 1)], 1);
        csr_src[pos] = (int)(e >> BSHIFT);
    }
}

// ---------------- prescale layer-1 input: xs = dinv[v] * x[v] (fp32) ----------------
__global__ void prescale_kernel(const float* __restrict__ x, const float* __restrict__ dinv,
                                float* __restrict__ xs, int n) {
    int i = blockIdx.x * blockDim.x + threadIdx.x;   // over n*2 float4s
    if (i >= n * 2) return;
    float dv = dinv[i >> 1];
    float4 v = ((const float4*)x)[i];
    ((float4*)xs)[i] = make_float4(v.x * dv, v.y * dv, v.z * dv, v.w * dv);
}

// ---------------- layer-1 aggregation: fp32 in, fp16 out (FIN=8, G=2) ----------------
__global__ void agg8_kernel(const float* __restrict__ hs, const int* __restrict__ row_off,
                            const int* __restrict__ deg, const float* __restrict__ dinv,
                            const int* __restrict__ csr_src, float2* __restrict__ out, int n) {
    int idx = blockIdx.x * blockDim.x + threadIdx.x;
    if (idx >= n * 2) return;
    int v = idx >> 1;
    int c = idx & 1;
    const float4* h4 = (const float4*)hs;
    float4 acc = h4[(size_t)v * 2 + c];
    int start = row_off[v], cnt = deg[v];
    const int* __restrict__ row = csr_src + start;
    int j = 0;
    for (; j + 4 <= cnt; j += 4) {
        float4 a0 = h4[(size_t)row[j] * 2 + c];
        float4 a1 = h4[(size_t)row[j + 1] * 2 + c];
        float4 a2 = h4[(size_t)row[j + 2] * 2 + c];
        float4 a3 = h4[(size_t)row[j + 3] * 2 + c];
        acc.x += (a0.x + a1.x) + (a2.x + a3.x);
        acc.y += (a0.y + a1.y) + (a2.y + a3.y);
        acc.z += (a0.z + a1.z) + (a2.z + a3.z);
        acc.w += (a0.w + a1.w) + (a2.w + a3.w);
    }
    for (; j < cnt; ++j) {
        float4 a = h4[(size_t)row[j] * 2 + c];
        acc.x += a.x; acc.y += a.y; acc.z += a.z; acc.w += a.w;
    }
    float dv = dinv[v];
    union { float2 f2; __half2 h2[2]; } u;
    u.h2[0] = __floats2half2_rn(acc.x * dv, acc.y * dv);
    u.h2[1] = __floats2half2_rn(acc.z * dv, acc.w * dv);
    out[idx] = u.f2;        // row = 8 halfs = 2 float2 units
}

// ---------------- fp16 aggregation: out[v] = dinv[v]*(hs[v] + sum_in hs[src]) -----------
// G = FIN/8 threads per node, 16B (8-half) loads, fp32 accumulate.
template<int FIN>
__global__ void agg_h_kernel(const float4* __restrict__ hs, const int* __restrict__ row_off,
                             const int* __restrict__ deg, const float* __restrict__ dinv,
                             const int* __restrict__ csr_src, float4* __restrict__ out, int n) {
    constexpr int G = FIN / 8;
    int idx = blockIdx.x * blockDim.x + threadIdx.x;
    if (idx >= n * G) return;
    int v = idx / G;
    int c = idx % G;
    float a[8];
    { H8 h; h.f4 = hs[(size_t)v * G + c]; h8_to_f(h, a); }
    int start = row_off[v], cnt = deg[v];
    const int* __restrict__ row = csr_src + start;
    int j = 0;
    for (; j + 4 <= cnt; j += 4) {
        H8 h0, h1, h2, h3;
        h0.f4 = hs[(size_t)row[j] * G + c];
        h1.f4 = hs[(size_t)row[j + 1] * G + c];
        h2.f4 = hs[(size_t)row[j + 2] * G + c];
        h3.f4 = hs[(size_t)row[j + 3] * G + c];
        float f0[8], f1[8], f2[8], f3[8];
        h8_to_f(h0, f0); h8_to_f(h1, f1); h8_to_f(h2, f2); h8_to_f(h3, f3);
#pragma unroll
        for (int k = 0; k < 8; ++k) a[k] += (f0[k] + f1[k]) + (f2[k] + f3[k]);
    }
    for (; j < cnt; ++j) {
        H8 h; h.f4 = hs[(size_t)row[j] * G + c];
        float f[8]; h8_to_f(h, f);
#pragma unroll
        for (int k = 0; k < 8; ++k) a[k] += f[k];
    }
    float dv = dinv[v];
#pragma unroll
    for (int k = 0; k < 8; ++k) a[k] *= dv;
    H8 o = f_to_h8(a);
    out[(size_t)v * G + c] = o.f4;
}

// ---------------- fused matmul + bias + prelu; fp16 in/out, fp32 math ----------------
template<int FIN, int FOUT, bool SCALE>
__global__ __launch_bounds__(256) void matmul_kernel(
    const float4* __restrict__ tin, const float* __restrict__ W,
    const float* __restrict__ bias, const float* __restrict__ slope,
    const float* __restrict__ dinv, float2* __restrict__ hout, int n) {
    constexpr int TPN = FOUT / 4;            // threads per node (4 outputs each)
    constexpr int NPB = (256 / TPN) * 4;     // nodes per block
    __shared__ float4 Wl[FIN * TPN];
    const float4* Wg = (const float4*)W;
    for (int i = threadIdx.x; i < FIN * TPN; i += 256) Wl[i] = Wg[i];
    __syncthreads();
    int t = threadIdx.x;
    int grp = t / TPN;
    int f4 = t % TPN;
    int v0 = blockIdx.x * NPB + grp * 4;
    float s = slope ? *slope : 1.0f;
    float4 bv = ((const float4*)bias)[f4];
    float4 acc[4];
#pragma unroll
    for (int nn = 0; nn < 4; ++nn) acc[nn] = bv;
#pragma unroll
    for (int i = 0; i < FIN; i += 8) {
        float r[4][8];
#pragma unroll
        for (int nn = 0; nn < 4; ++nn) {
            int v = v0 + nn;
            H8 h;
            h.f4 = (v < n) ? tin[(size_t)v * (FIN / 8) + (i >> 3)]
                           : make_float4(0.f, 0.f, 0.f, 0.f);
            h8_to_f(h, r[nn]);
        }
#pragma unroll
        for (int k = 0; k < 8; ++k) {
            float4 wv = Wl[(i + k) * TPN + f4];
#pragma unroll
            for (int nn = 0; nn < 4; ++nn) {
                float rk = r[nn][k];
                acc[nn].x += wv.x * rk;
                acc[nn].y += wv.y * rk;
                acc[nn].z += wv.z * rk;
                acc[nn].w += wv.w * rk;
            }
        }
    }
#pragma unroll
    for (int nn = 0; nn < 4; ++nn) {
        int v = v0 + nn;
        if (v < n) {
            float m = SCALE ? dinv[v] : 1.0f;
            float ox = (fmaxf(acc[nn].x, 0.f) + s * fminf(acc[nn].x, 0.f)) * m;
            float oy = (fmaxf(acc[nn].y, 0.f) + s * fminf(acc[nn].y, 0.f)) * m;
            float oz = (fmaxf(acc[nn].z, 0.f) + s * fminf(acc[nn].z, 0.f)) * m;
            float ow = (fmaxf(acc[nn].w, 0.f) + s * fminf(acc[nn].w, 0.f)) * m;
            union { float2 f2; __half2 h2[2]; } u;
            u.h2[0] = __floats2half2_rn(ox, oy);
            u.h2[1] = __floats2half2_rn(oz, ow);
            hout[(size_t)v * TPN + f4] = u.f2;   // row = FOUT halfs = TPN float2s
        }
    }
}

// ---------------- fused layer-4 aggregation + pooling (fp16 in, LDS-reduced flush) ------
#define APCHUNK 64
__global__ __launch_bounds__(256) void agg_pool_kernel(
    const float4* __restrict__ hs, const int* __restrict__ row_off,
    const int* __restrict__ deg, const float* __restrict__ dinv,
    const int* __restrict__ csr_src, const int* __restrict__ batch,
    float* __restrict__ sums, float* __restrict__ cnt, int n) {
    __shared__ float lacc[NG * 64];   // [graph][feature] 16 KB
    __shared__ float lcnt[NG];
    int tid = threadIdx.x;
    int c = tid & 7;         // H8 column (64 halfs = 8 H8)
    int r = tid >> 3;        // row stream 0..31
    int start = blockIdx.x * APCHUNK;
    if (start >= n) return;
    int end = start + APCHUNK; if (end > n) end = n;
    for (int i = tid; i < NG * 64; i += 256) lacc[i] = 0.f;
    if (tid < NG) lcnt[tid] = 0.f;
    __syncthreads();
    float pacc[8] = {0.f, 0.f, 0.f, 0.f, 0.f, 0.f, 0.f, 0.f};
    float rc = 0.f;
    int curg = -1;
    for (int v = start + r; v < end; v += 32) {
        int g = batch[v];
        if (g != curg) {
            if (curg >= 0) {
                float* lp = &lacc[curg * 64 + c * 8];
#pragma unroll
                for (int k = 0; k < 8; ++k) { atomicAdd(lp + k, pacc[k]); pacc[k] = 0.f; }
                if (c == 0) atomicAdd(&lcnt[curg], rc);
                rc = 0.f;
            }
            curg = g;
        }
        float a[8];
        { H8 h; h.f4 = hs[(size_t)v * 8 + c]; h8_to_f(h, a); }
        int s0 = row_off[v], dcnt = deg[v];
        const int* __restrict__ row = csr_src + s0;
        int j = 0;
        for (; j + 4 <= dcnt; j += 4) {
            H8 h0, h1, h2, h3;
            h0.f4 = hs[(size_t)row[j] * 8 + c];
            h1.f4 = hs[(size_t)row[j + 1] * 8 + c];
            h2.f4 = hs[(size_t)row[j + 2] * 8 + c];
            h3.f4 = hs[(size_t)row[j + 3] * 8 + c];
            float f0[8], f1[8], f2[8], f3[8];
            h8_to_f(h0, f0); h8_to_f(h1, f1); h8_to_f(h2, f2); h8_to_f(h3, f3);
#pragma unroll
            for (int k = 0; k < 8; ++k) a[k] += (f0[k] + f1[k]) + (f2[k] + f3[k]);
        }
        for (; j < dcnt; ++j) {
            H8 h; h.f4 = hs[(size_t)row[j] * 8 + c];
            float f[8]; h8_to_f(h, f);
#pragma unroll
            for (int k = 0; k < 8; ++k) a[k] += f[k];
        }
        float dv = dinv[v];
#pragma unroll
        for (int k = 0; k < 8; ++k) pacc[k] += a[k] * dv;
        rc += 1.f;
    }
    if (curg >= 0) {
        float* lp = &lacc[curg * 64 + c * 8];
#pragma unroll
        for (int k = 0; k < 8; ++k) atomicAdd(lp + k, pacc[k]);
        if (c == 0) atomicAdd(&lcnt[curg], rc);
    }
    __syncthreads();
    // flush only graphs present in this block's node range (batch sorted)
    int gmin = batch[start];
    int gmax = batch[end - 1];
    int span = gmax - gmin + 1;
    for (int idx = tid; idx < span * 64; idx += 256) {
        int g = gmin + idx / 64;
        int f = idx % 64;
        float val = lacc[g * 64 + f];
        if (val != 0.f) atomicAdd(&sums[g * 64 + f], val);
    }
    for (int g = gmin + tid; g <= gmax; g += 256) {
        float v = lcnt[g];
        if (v != 0.f) atomicAdd(&cnt[g], v);
    }
}

// ---------------- head: out[g] = (P[g] @ (W4@Wlin)) / cnt[g] + (b4@Wlin + blin) ----------
__global__ __launch_bounds__(256) void head_kernel(
    const float* __restrict__ P, const float* __restrict__ cnt,
    const float* __restrict__ W4, const float* __restrict__ b4,
    const float* __restrict__ Wlin, const float* __restrict__ blin,
    float* __restrict__ out) {
    __shared__ float M[64 * 4];   // W4 @ Wlin
    __shared__ float bb[4];       // b4 @ Wlin + blin
    int t = threadIdx.x;          // 256 = 64 * 4
    {
        int k = t >> 2, cc = t & 3;
        float m = 0.f;
        for (int j = 0; j < 128; ++j) m += W4[k * 128 + j] * Wlin[j * 4 + cc];
        M[k * 4 + cc] = m;
    }
    if (t < 4) {
        float v = blin[t];
        for (int j = 0; j < 128; ++j) v += b4[j] * Wlin[j * 4 + t];
        bb[t] = v;
    }
    __syncthreads();
    int g = t >> 2, cc = t & 3;
    float a = 0.f;
    for (int k = 0; k < 64; ++k) a += P[g * 64 + k] * M[k * 4 + cc];
    out[g * 4 + cc] = a / fmaxf(cnt[g], 1.f) + bb[cc];
}

extern "C" void kernel_launch(void* const* d_in, const int* in_sizes, int n_in,
                              void* d_out, int out_size, void* d_ws, size_t ws_size,
                              hipStream_t stream) {
    const float* x    = (const float*)d_in[0];
    const int* esrc   = (const int*)d_in[1];
    const int* edst   = (const int*)d_in[2];
    const int* batch  = (const int*)d_in[3];
    const float* W1 = (const float*)d_in[4],  *b1 = (const float*)d_in[5];
    const float* W2 = (const float*)d_in[6],  *b2 = (const float*)d_in[7];
    const float* W3 = (const float*)d_in[8],  *b3 = (const float*)d_in[9];
    const float* W4 = (const float*)d_in[10], *b4 = (const float*)d_in[11];
    const float* a1 = (const float*)d_in[12];
    const float* a2 = (const float*)d_in[13];
    const float* a3 = (const float*)d_in[14];
    const float* Wlin = (const float*)d_in[15], *blin = (const float*)d_in[16];
    float* out = (float*)d_out;

    const int N = NN, E = NE;
    const int NB = (N + 1023) / 1024;                   // node-scan blocks (98)
    const int NBIN = (E + BIN_CHUNK - 1) / BIN_CHUNK;   // 196

    // workspace carve-up
    char* w = (char*)d_ws;
    size_t off = 0;
    auto alloc = [&](size_t bytes) { size_t r = off; off += (bytes + 255) & ~(size_t)255; return r; };
    size_t o_bcnt = alloc((size_t)NBUCK * 4);      // needs zero
    size_t o_pool = alloc((size_t)NG * 64 * 4);    // needs zero (pooled T sums)
    size_t o_cnt  = alloc((size_t)NG * 4);         // needs zero
    size_t zero_bytes = off;
    size_t o_deg  = alloc((size_t)N * 4);
    size_t o_dinv = alloc((size_t)N * 4);
    size_t o_roff = alloc((size_t)N * 4);
    size_t o_boff = alloc((size_t)NBUCK * 4);
    size_t o_bcur = alloc((size_t)NBUCK * 4);
    size_t o_bsum = alloc((size_t)128 * 4);
    size_t o_csrc = alloc((size_t)E * 4);
    size_t o_bin  = alloc((size_t)E * 4);          // packed (src<<7)|dst_low
    size_t o_X    = alloc((size_t)N * 8 * 4);      // prescaled x (fp32)
    size_t o_A    = alloc((size_t)N * 64 * 2);     // activations fp16 (max 64 halfs)
    size_t o_T    = alloc((size_t)N * 32 * 2);     // agg output fp16 (max 32 halfs)
    (void)ws_size;
    int*      bcnt   = (int*)(w + o_bcnt);
    float*    pool   = (float*)(w + o_pool);
    float*    cnt    = (float*)(w + o_cnt);
    int*      deg    = (int*)(w + o_deg);
    float*    dinv   = (float*)(w + o_dinv);
    int*      roff   = (int*)(w + o_roff);
    int*      boff   = (int*)(w + o_boff);
    int*      bcur   = (int*)(w + o_bcur);
    int*      bsum   = (int*)(w + o_bsum);
    int*      csrc   = (int*)(w + o_csrc);
    unsigned* binned = (unsigned*)(w + o_bin);
    float*    XS     = (float*)(w + o_X);
    char*     A      = (char*)(w + o_A);
    char*     T      = (char*)(w + o_T);

    hipMemsetAsync(w, 0, zero_bytes, stream);

    // ---- CSR build via dst-bucket binning (once, reused by all 4 layers) ----
    bucket_hist_kernel<<<256, 256, 0, stream>>>(edst, bcnt, E);
    bucket_scan_kernel<<<1, 1024, 0, stream>>>(bcnt, boff, bcur);
    bin_kernel<<<NBIN, 256, 0, stream>>>(esrc, edst, bcur, binned, E);
    deg_dinv_kernel<<<NBUCK, 256, 0, stream>>>(binned, boff, bcnt, deg, dinv, N);
    scan1_kernel<<<NB, 1024, 0, stream>>>(deg, roff, bsum, N);
    scan2_kernel<<<1, 128, 0, stream>>>(bsum, NB);
    scan3_kernel<<<(N + 255) / 256, 256, 0, stream>>>(roff, bsum, N);
    build2_kernel<<<NBUCK, 256, 0, stream>>>(binned, boff, bcnt, roff, csrc, N);

    // ---- layer 1: agg(dinv*x)[8] @ W1 -> 16, prelu a1, output pre-scaled (fp16) ----
    prescale_kernel<<<(N * 2 + 255) / 256, 256, 0, stream>>>(x, dinv, XS, N);
    agg8_kernel<<<(N * 2 + 255) / 256, 256, 0, stream>>>(XS, roff, deg, dinv, csrc, (float2*)T, N);
    matmul_kernel<8, 16, true><<<(N + 255) / 256, 256, 0, stream>>>(
        (const float4*)T, W1, b1, a1, dinv, (float2*)A, N);

    // ---- layer 2 ----
    agg_h_kernel<16><<<(N * 2 + 255) / 256, 256, 0, stream>>>(
        (const float4*)A, roff, deg, dinv, csrc, (float4*)T, N);
    matmul_kernel<16, 32, true><<<(N + 127) / 128, 256, 0, stream>>>(
        (const float4*)T, W2, b2, a2, dinv, (float2*)A, N);

    // ---- layer 3 ----
    agg_h_kernel<32><<<(N * 4 + 255) / 256, 256, 0, stream>>>(
        (const float4*)A, roff, deg, dinv, csrc, (float4*)T, N);
    matmul_kernel<32, 64, true><<<(N + 63) / 64, 256, 0, stream>>>(
        (const float4*)T, W3, b3, a3, dinv, (float2*)A, N);

    // ---- layer 4: fused agg + pool (T never materialized; matmul folded into head) ----
    agg_pool_kernel<<<(N + APCHUNK - 1) / APCHUNK, 256, 0, stream>>>(
        (const float4*)A, roff, deg, dinv, csrc, batch, pool, cnt, N);
    head_kernel<<<1, 256, 0, stream>>>(pool, cnt, W4, b4, Wlin, blin, out);
}